// Round 7
// baseline (420.320 us; speedup 1.0000x reference)
//
#include <hip/hip_runtime.h>
#include <hip/hip_bf16.h>
#include <math.h>

#define DIMD 1024
#define LSEQ 2048
#define BATCH 4
#define NHEAD 8
#define HD 128
#define NROWS (BATCH*LSEQ)   // 8192
#define PROJC (5*DIMD)       // 5120
#define BRC (2*DIMD)         // 2048

typedef __attribute__((ext_vector_type(8))) short short8;
typedef __attribute__((ext_vector_type(4))) short short4v;
typedef __attribute__((ext_vector_type(4))) float floatx4;

__device__ __forceinline__ float bf2f(short s) {
  unsigned int u = ((unsigned int)(unsigned short)s) << 16;
  return __builtin_bit_cast(float, u);
}
__device__ __forceinline__ short f2bf(float f) {
  unsigned int u = __builtin_bit_cast(unsigned int, f);
  unsigned int lsb = (u >> 16) & 1u;
  u += 0x7fffu + lsb;
  return (short)(u >> 16);
}

// global->LDS direct DMA, 16B per lane. LDS dest is wave-uniform base;
// HW scatters lane i to lds + i*16.
__device__ __forceinline__ void gl2lds16(const short* g, short* l) {
  __builtin_amdgcn_global_load_lds(
      (const __attribute__((address_space(1))) unsigned int*)(unsigned long long)g,
      (__attribute__((address_space(3))) unsigned int*)(unsigned int)(unsigned long long)l,
      16, 0, 0);
}

// ---------------- fp32 -> bf16 weight conversion ----------------
__global__ __launch_bounds__(256) void cvt_kernel(const float* __restrict__ src,
    short* __restrict__ dst, int n4) {
  int i = blockIdx.x * 256 + threadIdx.x;
  if (i >= n4) return;
  float4 v = *(const float4*)(src + (size_t)i * 4);
  short4v o;
  o[0] = f2bf(v.x); o[1] = f2bf(v.y); o[2] = f2bf(v.z); o[3] = f2bf(v.w);
  *(short4v*)(dst + (size_t)i * 4) = o;
}

// ---------------- LayerNorm: x fp32 [8192,1024] -> h bf16 ----------------
__global__ __launch_bounds__(256) void ln_kernel(const float* __restrict__ x,
    const float* __restrict__ gamma, const float* __restrict__ beta,
    short* __restrict__ h) {
  int row = blockIdx.x;
  int c = threadIdx.x * 4;
  const float* xr = x + (size_t)row * DIMD;
  float4 v = *(const float4*)(xr + c);
  float f[4] = {v.x, v.y, v.z, v.w};
  float sum = 0.f, sq = 0.f;
  for (int i = 0; i < 4; ++i) { sum += f[i]; sq += f[i]*f[i]; }
  for (int off = 1; off < 64; off <<= 1) {
    sum += __shfl_xor(sum, off);
    sq  += __shfl_xor(sq, off);
  }
  __shared__ float red[8];
  int wid = threadIdx.x >> 6;
  if ((threadIdx.x & 63) == 0) { red[wid*2] = sum; red[wid*2+1] = sq; }
  __syncthreads();
  sum = red[0]+red[2]+red[4]+red[6];
  sq  = red[1]+red[3]+red[5]+red[7];
  float mu = sum * (1.0f/DIMD);
  float var = sq * (1.0f/DIMD) - mu*mu;
  float rstd = rsqrtf(var + 1e-5f);
  float4 g = *(const float4*)(gamma + c);
  float4 bb = *(const float4*)(beta + c);
  float gg[4] = {g.x, g.y, g.z, g.w};
  float bv[4] = {bb.x, bb.y, bb.z, bb.w};
  short4v o;
  for (int i = 0; i < 4; ++i)
    o[i] = f2bf((f[i] - mu) * rstd * gg[i] + bv[i]);
  *(short4v*)(h + (size_t)row * DIMD + c) = o;
}

// ------- GEMM: C[M,N] = A[M,K] * W[N,K]^T, A/W bf16. BK=64 (32 MFMA per
// barrier-pair), rot-swizzled 8-slot LDS rows (2-way max = free).
// MODE 0: C bf16 scalar epilogue. MODE 1: C fp32 = acc + X. -------
template<int MODE>
__global__ __launch_bounds__(256) void gemm_bt(const short* __restrict__ A,
    const short* __restrict__ W, const float* __restrict__ X,
    void* __restrict__ Cv, int M, int N, int K) {
  __shared__ __align__(16) short As[128*64];
  __shared__ __align__(16) short Ws[128*64];
  int tid = threadIdx.x;
  int row0 = blockIdx.y * 128;
  int col0 = blockIdx.x * 128;
  int lane = tid & 63, wv = tid >> 6;
  int wr = (wv >> 1) * 64, wc = (wv & 1) * 64;
  int quad = lane >> 4, l16 = lane & 15;
  floatx4 acc[4][4] = {};
  int srow = lane >> 3;
  int gq = ((lane & 7) - srow) & 7;
  const short* Ag = A + (size_t)(row0 + wv*8 + srow) * K + gq*8;
  const short* Wg = W + (size_t)(col0 + wv*8 + srow) * K + gq*8;
  short* Al = As + wv*8*64;
  short* Wl = Ws + wv*8*64;
  int qsr0 = (((quad)     + (l16 & 7)) & 7) * 8;
  int qsr1 = (((quad + 4) + (l16 & 7)) & 7) * 8;
  for (int k0 = 0; k0 < K; k0 += 64) {
    __syncthreads();
    for (int c = 0; c < 4; ++c) {
      gl2lds16(Ag + k0 + (size_t)(c*32)*K, Al + c*32*64);
      gl2lds16(Wg + k0 + (size_t)(c*32)*K, Wl + c*32*64);
    }
    __syncthreads();
    short8 af[4], wf[4];
    for (int i = 0; i < 4; ++i) af[i] = *(const short8*)&As[(wr + i*16 + l16)*64 + qsr0];
    for (int j = 0; j < 4; ++j) wf[j] = *(const short8*)&Ws[(wc + j*16 + l16)*64 + qsr0];
    for (int i = 0; i < 4; ++i)
      for (int j = 0; j < 4; ++j)
        acc[i][j] = __builtin_amdgcn_mfma_f32_16x16x32_bf16(af[i], wf[j], acc[i][j], 0, 0, 0);
    for (int i = 0; i < 4; ++i) af[i] = *(const short8*)&As[(wr + i*16 + l16)*64 + qsr1];
    for (int j = 0; j < 4; ++j) wf[j] = *(const short8*)&Ws[(wc + j*16 + l16)*64 + qsr1];
    for (int i = 0; i < 4; ++i)
      for (int j = 0; j < 4; ++j)
        acc[i][j] = __builtin_amdgcn_mfma_f32_16x16x32_bf16(af[i], wf[j], acc[i][j], 0, 0, 0);
  }
  for (int i = 0; i < 4; ++i) {
    int r0 = row0 + wr + i*16 + quad*4;
    for (int j = 0; j < 4; ++j) {
      int cc = col0 + wc + j*16 + l16;
      for (int r = 0; r < 4; ++r) {
        float v = acc[i][j][r];
        size_t idx = (size_t)(r0 + r) * N + cc;
        if (MODE == 0) {
          ((short*)Cv)[idx] = f2bf(v);
        } else {
          ((float*)Cv)[idx] = v + X[idx];
        }
      }
    }
  }
}

// ------------- GELU branch: branch[:,0:1024] = lin * gelu(pre), bf16 -------------
__global__ __launch_bounds__(256) void gelu_kernel(const short* __restrict__ proj,
    short* __restrict__ branch) {
  int row = blockIdx.x;
  int c = threadIdx.x * 4;
  const short* pr = proj + (size_t)row * PROJC;
  short4v lin = *(const short4v*)(pr + 3*DIMD + c);
  short4v pre = *(const short4v*)(pr + 4*DIMD + c);
  short4v o;
  for (int i = 0; i < 4; ++i) {
    float xx = bf2f(pre[i]);
    float g = 0.5f * xx * (1.f + erff(xx * 0.70710678118654752f));
    o[i] = f2bf(bf2f(lin[i]) * g);
  }
  *(short4v*)(branch + (size_t)row * BRC + c) = o;
}

// ------------- V transpose: vt[bh][d][l] from proj v-slice (bf16) -------------
__global__ __launch_bounds__(256) void vt_kernel(const short* __restrict__ proj,
    short* __restrict__ vt) {
  int bh = blockIdx.y;
  int b = bh >> 3, hh = bh & 7;
  int l0 = blockIdx.x * 64;
  __shared__ short Ls[64][136];
  int tid = threadIdx.x;
  int r = tid >> 4, c = (tid & 15) * 8;
  const short* Vp = proj + (size_t)b * LSEQ * PROJC + 2*DIMD + hh*HD;
  for (int p = 0; p < 4; ++p)
    *(short8*)&Ls[r + p*16][c] = *(const short8*)(Vp + (size_t)(l0 + r + p*16) * PROJC + c);
  __syncthreads();
  int d = tid >> 1, lh = (tid & 1) * 32;
  short* outp = vt + ((size_t)bh * HD + d) * LSEQ + l0 + lh;
  for (int g = 0; g < 4; ++g) {
    short8 o;
    for (int j = 0; j < 8; ++j) o[j] = Ls[lh + g*8 + j][d];
    *(short8*)(outp + g*8) = o;
  }
}

// ------------- Flash attention, p=2 power-softmax, causal.
// Sequential q-pairing: block bid handles qa=2*bid (waves 0-3), qb=2*bid+1
// (waves 4-7); NT=2*bid+2 staged tiles; heavy blocks launch first.
// Register-prefetch of next K/V tile overlaps global latency with compute.
// Merged 64-col inner step: one Ps round-trip per staged tile. -------------
__global__ __launch_bounds__(512) void attn_kernel(const short* __restrict__ proj,
    const short* __restrict__ vt, short* __restrict__ branch) {
  int bh = blockIdx.y;
  int b = bh >> 3, hh = bh & 7;
  int bid = 15 - blockIdx.x;       // heavy-first
  int tid = threadIdx.x;           // 0..511
  int wv = tid >> 6, lane = tid & 63, quad = lane >> 4, l16 = lane & 15;
  int qsel = 2*bid + ((wv < 4) ? 0 : 1);
  int qw = qsel * 64 + (wv & 3) * 16;

  const short* Qp  = proj + (size_t)b * LSEQ * PROJC + hh*HD;
  const short* Kp  = Qp + DIMD;
  const short* VTp = vt + (size_t)bh * HD * LSEQ;

  __shared__ short Ks[64][132];
  __shared__ short Vs[128][68];
  __shared__ short Ps[8][16][68];

  short8 qf[4];
  {
    const short* qrow = Qp + (size_t)(qw + l16) * PROJC;
    for (int s = 0; s < 4; ++s) qf[s] = *(const short8*)(qrow + s*32 + quad*8);
  }
  float lsum[4] = {0.f, 0.f, 0.f, 0.f};
  floatx4 O[8] = {};

  const float scale = 0.08838834764831845f;  // 1/sqrt(128)
  int NT = 2*bid + 2;
  int krow = tid >> 4;             // 0..31
  int kcol = (tid & 15) * 8;
  int vd = tid >> 2;               // 0..127
  int vk = (tid & 3) * 8;
  // prefetch tile 0
  short8 pk0 = *(const short8*)(Kp + (size_t)krow * PROJC + kcol);
  short8 pk1 = *(const short8*)(Kp + (size_t)(32 + krow) * PROJC + kcol);
  short8 pv0 = *(const short8*)(VTp + (size_t)vd * LSEQ + vk);
  short8 pv1 = *(const short8*)(VTp + (size_t)vd * LSEQ + 32 + vk);
  for (int kt = 0; kt < NT; ++kt) {
    int kb64 = kt * 64;
    __syncthreads();
    *(short8*)&Ks[krow][kcol]      = pk0;
    *(short8*)&Ks[krow + 32][kcol] = pk1;
    *(short8*)&Vs[vd][vk]          = pv0;
    *(short8*)&Vs[vd][32 + vk]     = pv1;
    __syncthreads();
    if (kt + 1 < NT) {             // issue next-tile loads; latency hides under compute
      int nb = kb64 + 64;
      pk0 = *(const short8*)(Kp + (size_t)(nb + krow) * PROJC + kcol);
      pk1 = *(const short8*)(Kp + (size_t)(nb + 32 + krow) * PROJC + kcol);
      pv0 = *(const short8*)(VTp + (size_t)vd * LSEQ + nb + vk);
      pv1 = *(const short8*)(VTp + (size_t)vd * LSEQ + nb + 32 + vk);
    }
    if (kb64 <= qw + 15) {
      floatx4 s[4] = {};
      for (int s4 = 0; s4 < 4; ++s4) {
        if (kb64 + s4*16 <= qw + 15) {
          for (int kk = 0; kk < 4; ++kk) {
            short8 kf = *(const short8*)&Ks[s4*16 + l16][kk*32 + quad*8];
            s[s4] = __builtin_amdgcn_mfma_f32_16x16x32_bf16(qf[kk], kf, s[s4], 0, 0, 0);
          }
        }
      }
      for (int s4 = 0; s4 < 4; ++s4) {
        int cc = kb64 + s4*16 + l16;
        for (int r = 0; r < 4; ++r) {
          int q = qw + quad*4 + r;
          float w = (cc <= q) ? __expf(s[s4][r] * scale) : 0.f;
          lsum[r] += w*w;
          Ps[wv][quad*4+r][s4*16 + l16] = f2bf(w);
        }
      }
      asm volatile("s_waitcnt lgkmcnt(0)" ::: "memory");
      short8 pf0 = *(const short8*)&Ps[wv][l16][quad*8];
      for (int t8 = 0; t8 < 8; ++t8) {
        short8 vf = *(const short8*)&Vs[t8*16 + l16][quad*8];
        O[t8] = __builtin_amdgcn_mfma_f32_16x16x32_bf16(pf0, vf, O[t8], 0, 0, 0);
      }
      if (kb64 + 32 <= qw + 15) {
        short8 pf1 = *(const short8*)&Ps[wv][l16][32 + quad*8];
        for (int t8 = 0; t8 < 8; ++t8) {
          short8 vf = *(const short8*)&Vs[t8*16 + l16][32 + quad*8];
          O[t8] = __builtin_amdgcn_mfma_f32_16x16x32_bf16(pf1, vf, O[t8], 0, 0, 0);
        }
      }
    }
  }
  for (int r = 0; r < 4; ++r) {
    float l = lsum[r];
    for (int off = 1; off < 16; off <<= 1) l += __shfl_xor(l, off);
    float inv = rsqrtf(l);
    int q = qw + quad*4 + r;
    short* orow = branch + ((size_t)(b*LSEQ + q)) * BRC + DIMD + hh*HD;
    for (int t8 = 0; t8 < 8; ++t8)
      orow[t8*16 + l16] = f2bf(O[t8][r] * inv);
  }
}

extern "C" void kernel_launch(void* const* d_in, const int* in_sizes, int n_in,
                              void* d_out, int out_size, void* d_ws, size_t ws_size,
                              hipStream_t stream) {
  const float* x     = (const float*)d_in[0];
  const float* gamma = (const float*)d_in[1];
  const float* beta  = (const float*)d_in[2];
  const float* w_qkv = (const float*)d_in[3];
  const float* w_out = (const float*)d_in[4];
  float* out = (float*)d_out;

  char* ws = (char*)d_ws;
  short* h      = (short*)ws;                                 // 16 MB (reused as vt)
  short* proj   = (short*)(ws + (size_t)16*1024*1024);        // 80 MB
  short* branch = (short*)(ws + (size_t)96*1024*1024);        // 32 MB
  short* wq     = (short*)(ws + (size_t)128*1024*1024);       // 10 MB
  short* wo     = (short*)(ws + (size_t)138*1024*1024);       // 4 MB
  short* vt     = h;  // h dead after GEMM1; alias for V^T

  cvt_kernel<<<(PROJC*DIMD/4 + 255)/256, 256, 0, stream>>>(w_qkv, wq, PROJC*DIMD/4);
  cvt_kernel<<<(DIMD*BRC/4 + 255)/256, 256, 0, stream>>>(w_out, wo, DIMD*BRC/4);
  ln_kernel<<<NROWS, 256, 0, stream>>>(x, gamma, beta, h);
  gemm_bt<0><<<dim3(PROJC/128, NROWS/128), 256, 0, stream>>>(h, wq, nullptr, proj,
                                                             NROWS, PROJC, DIMD);
  gelu_kernel<<<NROWS, 256, 0, stream>>>(proj, branch);
  vt_kernel<<<dim3(LSEQ/64, BATCH*NHEAD), 256, 0, stream>>>(proj, vt);
  attn_kernel<<<dim3(16, BATCH*NHEAD), 512, 0, stream>>>(proj, vt, branch);
  gemm_bt<1><<<dim3(DIMD/128, NROWS/128), 256, 0, stream>>>(branch, wo, x, out,
                                                            NROWS, DIMD, BRC);
}

// Round 9
// 401.753 us; speedup vs baseline: 1.0462x; 1.0462x over previous
//
#include <hip/hip_runtime.h>
#include <hip/hip_bf16.h>
#include <math.h>

#define DIMD 1024
#define LSEQ 2048
#define BATCH 4
#define NHEAD 8
#define HD 128
#define NROWS (BATCH*LSEQ)   // 8192
#define PROJC (5*DIMD)       // 5120
#define BRC (2*DIMD)         // 2048

typedef __attribute__((ext_vector_type(8))) short short8;
typedef __attribute__((ext_vector_type(4))) short short4v;
typedef __attribute__((ext_vector_type(4))) float floatx4;

__device__ __forceinline__ float bf2f(short s) {
  unsigned int u = ((unsigned int)(unsigned short)s) << 16;
  return __builtin_bit_cast(float, u);
}
__device__ __forceinline__ short f2bf(float f) {
  unsigned int u = __builtin_bit_cast(unsigned int, f);
  unsigned int lsb = (u >> 16) & 1u;
  u += 0x7fffu + lsb;
  return (short)(u >> 16);
}

// global->LDS direct DMA, 16B per lane. LDS dest is wave-uniform base;
// HW scatters lane i to lds + i*16.
__device__ __forceinline__ void gl2lds16(const short* g, short* l) {
  __builtin_amdgcn_global_load_lds(
      (const __attribute__((address_space(1))) unsigned int*)(unsigned long long)g,
      (__attribute__((address_space(3))) unsigned int*)(unsigned int)(unsigned long long)l,
      16, 0, 0);
}

// ---------------- fp32 -> bf16 weight conversion ----------------
__global__ __launch_bounds__(256) void cvt_kernel(const float* __restrict__ src,
    short* __restrict__ dst, int n4) {
  int i = blockIdx.x * 256 + threadIdx.x;
  if (i >= n4) return;
  float4 v = *(const float4*)(src + (size_t)i * 4);
  short4v o;
  o[0] = f2bf(v.x); o[1] = f2bf(v.y); o[2] = f2bf(v.z); o[3] = f2bf(v.w);
  *(short4v*)(dst + (size_t)i * 4) = o;
}

// ---------------- LayerNorm: x fp32 [8192,1024] -> h bf16 ----------------
__global__ __launch_bounds__(256) void ln_kernel(const float* __restrict__ x,
    const float* __restrict__ gamma, const float* __restrict__ beta,
    short* __restrict__ h) {
  int row = blockIdx.x;
  int c = threadIdx.x * 4;
  const float* xr = x + (size_t)row * DIMD;
  float4 v = *(const float4*)(xr + c);
  float f[4] = {v.x, v.y, v.z, v.w};
  float sum = 0.f, sq = 0.f;
  for (int i = 0; i < 4; ++i) { sum += f[i]; sq += f[i]*f[i]; }
  for (int off = 1; off < 64; off <<= 1) {
    sum += __shfl_xor(sum, off);
    sq  += __shfl_xor(sq, off);
  }
  __shared__ float red[8];
  int wid = threadIdx.x >> 6;
  if ((threadIdx.x & 63) == 0) { red[wid*2] = sum; red[wid*2+1] = sq; }
  __syncthreads();
  sum = red[0]+red[2]+red[4]+red[6];
  sq  = red[1]+red[3]+red[5]+red[7];
  float mu = sum * (1.0f/DIMD);
  float var = sq * (1.0f/DIMD) - mu*mu;
  float rstd = rsqrtf(var + 1e-5f);
  float4 g = *(const float4*)(gamma + c);
  float4 bb = *(const float4*)(beta + c);
  float gg[4] = {g.x, g.y, g.z, g.w};
  float bv[4] = {bb.x, bb.y, bb.z, bb.w};
  short4v o;
  for (int i = 0; i < 4; ++i)
    o[i] = f2bf((f[i] - mu) * rstd * gg[i] + bv[i]);
  *(short4v*)(h + (size_t)row * DIMD + c) = o;
}

// ------- GEMM: C[M,N] = A[M,K] * W[N,K]^T, A/W bf16. BK=64 (32 MFMA per
// barrier-pair), rot-swizzled 8-slot LDS rows (2-way max = free).
// MODE 0: C bf16 scalar epilogue. MODE 1: C fp32 = acc + X. -------
template<int MODE>
__global__ __launch_bounds__(256) void gemm_bt(const short* __restrict__ A,
    const short* __restrict__ W, const float* __restrict__ X,
    void* __restrict__ Cv, int M, int N, int K) {
  __shared__ __align__(16) short As[128*64];
  __shared__ __align__(16) short Ws[128*64];
  int tid = threadIdx.x;
  int row0 = blockIdx.y * 128;
  int col0 = blockIdx.x * 128;
  int lane = tid & 63, wv = tid >> 6;
  int wr = (wv >> 1) * 64, wc = (wv & 1) * 64;
  int quad = lane >> 4, l16 = lane & 15;
  floatx4 acc[4][4] = {};
  int srow = lane >> 3;
  int gq = ((lane & 7) - srow) & 7;
  const short* Ag = A + (size_t)(row0 + wv*8 + srow) * K + gq*8;
  const short* Wg = W + (size_t)(col0 + wv*8 + srow) * K + gq*8;
  short* Al = As + wv*8*64;
  short* Wl = Ws + wv*8*64;
  int qsr0 = (((quad)     + (l16 & 7)) & 7) * 8;
  int qsr1 = (((quad + 4) + (l16 & 7)) & 7) * 8;
  for (int k0 = 0; k0 < K; k0 += 64) {
    __syncthreads();
    for (int c = 0; c < 4; ++c) {
      gl2lds16(Ag + k0 + (size_t)(c*32)*K, Al + c*32*64);
      gl2lds16(Wg + k0 + (size_t)(c*32)*K, Wl + c*32*64);
    }
    __syncthreads();
    short8 af[4], wf[4];
    for (int i = 0; i < 4; ++i) af[i] = *(const short8*)&As[(wr + i*16 + l16)*64 + qsr0];
    for (int j = 0; j < 4; ++j) wf[j] = *(const short8*)&Ws[(wc + j*16 + l16)*64 + qsr0];
    for (int i = 0; i < 4; ++i)
      for (int j = 0; j < 4; ++j)
        acc[i][j] = __builtin_amdgcn_mfma_f32_16x16x32_bf16(af[i], wf[j], acc[i][j], 0, 0, 0);
    for (int i = 0; i < 4; ++i) af[i] = *(const short8*)&As[(wr + i*16 + l16)*64 + qsr1];
    for (int j = 0; j < 4; ++j) wf[j] = *(const short8*)&Ws[(wc + j*16 + l16)*64 + qsr1];
    for (int i = 0; i < 4; ++i)
      for (int j = 0; j < 4; ++j)
        acc[i][j] = __builtin_amdgcn_mfma_f32_16x16x32_bf16(af[i], wf[j], acc[i][j], 0, 0, 0);
  }
  for (int i = 0; i < 4; ++i) {
    int r0 = row0 + wr + i*16 + quad*4;
    for (int j = 0; j < 4; ++j) {
      int cc = col0 + wc + j*16 + l16;
      for (int r = 0; r < 4; ++r) {
        float v = acc[i][j][r];
        size_t idx = (size_t)(r0 + r) * N + cc;
        if (MODE == 0) {
          ((short*)Cv)[idx] = f2bf(v);
        } else {
          ((float*)Cv)[idx] = v + X[idx];
        }
      }
    }
  }
}

// ------------- GELU branch: branch[:,0:1024] = lin * gelu(pre), bf16 -------------
__global__ __launch_bounds__(256) void gelu_kernel(const short* __restrict__ proj,
    short* __restrict__ branch) {
  int row = blockIdx.x;
  int c = threadIdx.x * 4;
  const short* pr = proj + (size_t)row * PROJC;
  short4v lin = *(const short4v*)(pr + 3*DIMD + c);
  short4v pre = *(const short4v*)(pr + 4*DIMD + c);
  short4v o;
  for (int i = 0; i < 4; ++i) {
    float xx = bf2f(pre[i]);
    float g = 0.5f * xx * (1.f + erff(xx * 0.70710678118654752f));
    o[i] = f2bf(bf2f(lin[i]) * g);
  }
  *(short4v*)(branch + (size_t)row * BRC + c) = o;
}

// ------------- V transpose: vt[bh][d][l] from proj v-slice (bf16) -------------
__global__ __launch_bounds__(256) void vt_kernel(const short* __restrict__ proj,
    short* __restrict__ vt) {
  int bh = blockIdx.y;
  int b = bh >> 3, hh = bh & 7;
  int l0 = blockIdx.x * 64;
  __shared__ short Ls[64][136];
  int tid = threadIdx.x;
  int r = tid >> 4, c = (tid & 15) * 8;
  const short* Vp = proj + (size_t)b * LSEQ * PROJC + 2*DIMD + hh*HD;
  for (int p = 0; p < 4; ++p)
    *(short8*)&Ls[r + p*16][c] = *(const short8*)(Vp + (size_t)(l0 + r + p*16) * PROJC + c);
  __syncthreads();
  int d = tid >> 1, lh = (tid & 1) * 32;
  short* outp = vt + ((size_t)bh * HD + d) * LSEQ + l0 + lh;
  for (int g = 0; g < 4; ++g) {
    short8 o;
    for (int j = 0; j < 8; ++j) o[j] = Ls[lh + g*8 + j][d];
    *(short8*)(outp + g*8) = o;
  }
}

// ------------- Flash attention, p=2 power-softmax, causal, load-balanced.
// Pairing qa=bid (waves 0-3), qb=31-bid (waves 4-7): compute per block
// uniform at 33 tile-steps. Merged 64-col inner step (one Ps round-trip
// per staged tile, Ps row = 64 cols + 4 pad) + register prefetch. -------------
__global__ __launch_bounds__(512) void attn_kernel(const short* __restrict__ proj,
    const short* __restrict__ vt, short* __restrict__ branch) {
  int bh = blockIdx.y;
  int b = bh >> 3, hh = bh & 7;
  int bid = blockIdx.x;            // 0..15
  int tid = threadIdx.x;           // 0..511
  int wv = tid >> 6, lane = tid & 63, quad = lane >> 4, l16 = lane & 15;
  int qsel = (wv < 4) ? bid : (31 - bid);
  int qw = qsel * 64 + (wv & 3) * 16;

  const short* Qp  = proj + (size_t)b * LSEQ * PROJC + hh*HD;
  const short* Kp  = Qp + DIMD;
  const short* VTp = vt + (size_t)bh * HD * LSEQ;

  __shared__ short Ks[64][132];
  __shared__ short Vs[128][68];
  __shared__ short Ps[8][16][68];   // 64 data cols + 4 pad (PV reads cols 0..63!)

  short8 qf[4];
  {
    const short* qrow = Qp + (size_t)(qw + l16) * PROJC;
    for (int s = 0; s < 4; ++s) qf[s] = *(const short8*)(qrow + s*32 + quad*8);
  }
  float lsum[4] = {0.f, 0.f, 0.f, 0.f};
  floatx4 O[8] = {};

  const float scale = 0.08838834764831845f;  // 1/sqrt(128)
  int NT = 32 - bid;               // staged 64-wide tiles (qb's causal range)
  int krow = tid >> 4;             // 0..31
  int kcol = (tid & 15) * 8;
  int vd = tid >> 2;               // 0..127
  int vk = (tid & 3) * 8;
  // prefetch tile 0
  short8 pk0 = *(const short8*)(Kp + (size_t)krow * PROJC + kcol);
  short8 pk1 = *(const short8*)(Kp + (size_t)(32 + krow) * PROJC + kcol);
  short8 pv0 = *(const short8*)(VTp + (size_t)vd * LSEQ + vk);
  short8 pv1 = *(const short8*)(VTp + (size_t)vd * LSEQ + 32 + vk);
  for (int kt = 0; kt < NT; ++kt) {
    int kb64 = kt * 64;
    __syncthreads();
    *(short8*)&Ks[krow][kcol]      = pk0;
    *(short8*)&Ks[krow + 32][kcol] = pk1;
    *(short8*)&Vs[vd][vk]          = pv0;
    *(short8*)&Vs[vd][32 + vk]     = pv1;
    __syncthreads();
    if (kt + 1 < NT) {             // issue next-tile loads; latency hides under compute
      int nb = kb64 + 64;
      pk0 = *(const short8*)(Kp + (size_t)(nb + krow) * PROJC + kcol);
      pk1 = *(const short8*)(Kp + (size_t)(nb + 32 + krow) * PROJC + kcol);
      pv0 = *(const short8*)(VTp + (size_t)vd * LSEQ + nb + vk);
      pv1 = *(const short8*)(VTp + (size_t)vd * LSEQ + nb + 32 + vk);
    }
    if (kb64 <= qw + 15) {
      floatx4 s[4] = {};
      for (int s4 = 0; s4 < 4; ++s4) {
        if (kb64 + s4*16 <= qw + 15) {
          for (int kk = 0; kk < 4; ++kk) {
            short8 kf = *(const short8*)&Ks[s4*16 + l16][kk*32 + quad*8];
            s[s4] = __builtin_amdgcn_mfma_f32_16x16x32_bf16(qf[kk], kf, s[s4], 0, 0, 0);
          }
        }
      }
      for (int s4 = 0; s4 < 4; ++s4) {
        int cc = kb64 + s4*16 + l16;
        for (int r = 0; r < 4; ++r) {
          int q = qw + quad*4 + r;
          float w = (cc <= q) ? __expf(s[s4][r] * scale) : 0.f;
          lsum[r] += w*w;
          Ps[wv][quad*4+r][s4*16 + l16] = f2bf(w);
        }
      }
      asm volatile("s_waitcnt lgkmcnt(0)" ::: "memory");
      short8 pf0 = *(const short8*)&Ps[wv][l16][quad*8];
      for (int t8 = 0; t8 < 8; ++t8) {
        short8 vf = *(const short8*)&Vs[t8*16 + l16][quad*8];
        O[t8] = __builtin_amdgcn_mfma_f32_16x16x32_bf16(pf0, vf, O[t8], 0, 0, 0);
      }
      if (kb64 + 32 <= qw + 15) {
        short8 pf1 = *(const short8*)&Ps[wv][l16][32 + quad*8];
        for (int t8 = 0; t8 < 8; ++t8) {
          short8 vf = *(const short8*)&Vs[t8*16 + l16][32 + quad*8];
          O[t8] = __builtin_amdgcn_mfma_f32_16x16x32_bf16(pf1, vf, O[t8], 0, 0, 0);
        }
      }
    }
  }
  for (int r = 0; r < 4; ++r) {
    float l = lsum[r];
    for (int off = 1; off < 16; off <<= 1) l += __shfl_xor(l, off);
    float inv = rsqrtf(l);
    int q = qw + quad*4 + r;
    short* orow = branch + ((size_t)(b*LSEQ + q)) * BRC + DIMD + hh*HD;
    for (int t8 = 0; t8 < 8; ++t8)
      orow[t8*16 + l16] = f2bf(O[t8][r] * inv);
  }
}

extern "C" void kernel_launch(void* const* d_in, const int* in_sizes, int n_in,
                              void* d_out, int out_size, void* d_ws, size_t ws_size,
                              hipStream_t stream) {
  const float* x     = (const float*)d_in[0];
  const float* gamma = (const float*)d_in[1];
  const float* beta  = (const float*)d_in[2];
  const float* w_qkv = (const float*)d_in[3];
  const float* w_out = (const float*)d_in[4];
  float* out = (float*)d_out;

  char* ws = (char*)d_ws;
  short* h      = (short*)ws;                                 // 16 MB (reused as vt)
  short* proj   = (short*)(ws + (size_t)16*1024*1024);        // 80 MB
  short* branch = (short*)(ws + (size_t)96*1024*1024);        // 32 MB
  short* wq     = (short*)(ws + (size_t)128*1024*1024);       // 10 MB
  short* wo     = (short*)(ws + (size_t)138*1024*1024);       // 4 MB
  short* vt     = h;  // h dead after GEMM1; alias for V^T

  cvt_kernel<<<(PROJC*DIMD/4 + 255)/256, 256, 0, stream>>>(w_qkv, wq, PROJC*DIMD/4);
  cvt_kernel<<<(DIMD*BRC/4 + 255)/256, 256, 0, stream>>>(w_out, wo, DIMD*BRC/4);
  ln_kernel<<<NROWS, 256, 0, stream>>>(x, gamma, beta, h);
  gemm_bt<0><<<dim3(PROJC/128, NROWS/128), 256, 0, stream>>>(h, wq, nullptr, proj,
                                                             NROWS, PROJC, DIMD);
  gelu_kernel<<<NROWS, 256, 0, stream>>>(proj, branch);
  vt_kernel<<<dim3(LSEQ/64, BATCH*NHEAD), 256, 0, stream>>>(proj, vt);
  attn_kernel<<<dim3(16, BATCH*NHEAD), 512, 0, stream>>>(proj, vt, branch);
  gemm_bt<1><<<dim3(DIMD/128, NROWS/128), 256, 0, stream>>>(branch, wo, x, out,
                                                            NROWS, DIMD, BRC);
}

// Round 10
// 361.787 us; speedup vs baseline: 1.1618x; 1.1105x over previous
//
#include <hip/hip_runtime.h>
#include <hip/hip_bf16.h>
#include <math.h>

#define DIMD 1024
#define LSEQ 2048
#define BATCH 4
#define NHEAD 8
#define HD 128
#define NROWS (BATCH*LSEQ)   // 8192
#define PROJC (5*DIMD)       // 5120
#define BRC (2*DIMD)         // 2048

typedef __attribute__((ext_vector_type(8))) short short8;
typedef __attribute__((ext_vector_type(4))) short short4v;
typedef __attribute__((ext_vector_type(4))) float floatx4;

__device__ __forceinline__ float bf2f(short s) {
  unsigned int u = ((unsigned int)(unsigned short)s) << 16;
  return __builtin_bit_cast(float, u);
}
__device__ __forceinline__ short f2bf(float f) {
  unsigned int u = __builtin_bit_cast(unsigned int, f);
  unsigned int lsb = (u >> 16) & 1u;
  u += 0x7fffu + lsb;
  return (short)(u >> 16);
}

// global->LDS direct DMA, 16B per lane. LDS dest is wave-uniform base;
// HW scatters lane i to lds + i*16.
__device__ __forceinline__ void gl2lds16(const short* g, short* l) {
  __builtin_amdgcn_global_load_lds(
      (const __attribute__((address_space(1))) unsigned int*)(unsigned long long)g,
      (__attribute__((address_space(3))) unsigned int*)(unsigned int)(unsigned long long)l,
      16, 0, 0);
}

// ---------------- fp32 -> bf16 conversion of both weight tensors ----------------
__global__ __launch_bounds__(256) void cvt2_kernel(const float* __restrict__ s1,
    short* __restrict__ d1, int n1_4, const float* __restrict__ s2,
    short* __restrict__ d2, int n2_4) {
  int i = blockIdx.x * 256 + threadIdx.x;
  const float* src; short* dst;
  if (i < n1_4) { src = s1; dst = d1; }
  else { i -= n1_4; if (i >= n2_4) return; src = s2; dst = d2; }
  float4 v = *(const float4*)(src + (size_t)i * 4);
  short4v o;
  o[0] = f2bf(v.x); o[1] = f2bf(v.y); o[2] = f2bf(v.z); o[3] = f2bf(v.w);
  *(short4v*)(dst + (size_t)i * 4) = o;
}

// ---------------- LayerNorm: x fp32 [8192,1024] -> h bf16 ----------------
__global__ __launch_bounds__(256) void ln_kernel(const float* __restrict__ x,
    const float* __restrict__ gamma, const float* __restrict__ beta,
    short* __restrict__ h) {
  int row = blockIdx.x;
  int c = threadIdx.x * 4;
  const float* xr = x + (size_t)row * DIMD;
  float4 v = *(const float4*)(xr + c);
  float f[4] = {v.x, v.y, v.z, v.w};
  float sum = 0.f, sq = 0.f;
  for (int i = 0; i < 4; ++i) { sum += f[i]; sq += f[i]*f[i]; }
  for (int off = 1; off < 64; off <<= 1) {
    sum += __shfl_xor(sum, off);
    sq  += __shfl_xor(sq, off);
  }
  __shared__ float red[8];
  int wid = threadIdx.x >> 6;
  if ((threadIdx.x & 63) == 0) { red[wid*2] = sum; red[wid*2+1] = sq; }
  __syncthreads();
  sum = red[0]+red[2]+red[4]+red[6];
  sq  = red[1]+red[3]+red[5]+red[7];
  float mu = sum * (1.0f/DIMD);
  float var = sq * (1.0f/DIMD) - mu*mu;
  float rstd = rsqrtf(var + 1e-5f);
  float4 g = *(const float4*)(gamma + c);
  float4 bb = *(const float4*)(beta + c);
  float gg[4] = {g.x, g.y, g.z, g.w};
  float bv[4] = {bb.x, bb.y, bb.z, bb.w};
  short4v o;
  for (int i = 0; i < 4; ++i)
    o[i] = f2bf((f[i] - mu) * rstd * gg[i] + bv[i]);
  *(short4v*)(h + (size_t)row * DIMD + c) = o;
}

// ------- GEMM: C[M,N] = A[M,K] * W[N,K]^T, A/W bf16. BK=64 (32 MFMA per
// barrier-pair), rot-swizzled 8-slot LDS rows (2-way max = free).
// MODE 0: C bf16 scalar epilogue. MODE 1: C fp32 = acc + X. -------
template<int MODE>
__global__ __launch_bounds__(256) void gemm_bt(const short* __restrict__ A,
    const short* __restrict__ W, const float* __restrict__ X,
    void* __restrict__ Cv, int M, int N, int K) {
  __shared__ __align__(16) short As[128*64];
  __shared__ __align__(16) short Ws[128*64];
  int tid = threadIdx.x;
  int row0 = blockIdx.y * 128;
  int col0 = blockIdx.x * 128;
  int lane = tid & 63, wv = tid >> 6;
  int wr = (wv >> 1) * 64, wc = (wv & 1) * 64;
  int quad = lane >> 4, l16 = lane & 15;
  floatx4 acc[4][4] = {};
  int srow = lane >> 3;
  int gq = ((lane & 7) - srow) & 7;
  const short* Ag = A + (size_t)(row0 + wv*8 + srow) * K + gq*8;
  const short* Wg = W + (size_t)(col0 + wv*8 + srow) * K + gq*8;
  short* Al = As + wv*8*64;
  short* Wl = Ws + wv*8*64;
  int qsr0 = (((quad)     + (l16 & 7)) & 7) * 8;
  int qsr1 = (((quad + 4) + (l16 & 7)) & 7) * 8;
  for (int k0 = 0; k0 < K; k0 += 64) {
    __syncthreads();
    for (int c = 0; c < 4; ++c) {
      gl2lds16(Ag + k0 + (size_t)(c*32)*K, Al + c*32*64);
      gl2lds16(Wg + k0 + (size_t)(c*32)*K, Wl + c*32*64);
    }
    __syncthreads();
    short8 af[4], wf[4];
    for (int i = 0; i < 4; ++i) af[i] = *(const short8*)&As[(wr + i*16 + l16)*64 + qsr0];
    for (int j = 0; j < 4; ++j) wf[j] = *(const short8*)&Ws[(wc + j*16 + l16)*64 + qsr0];
    for (int i = 0; i < 4; ++i)
      for (int j = 0; j < 4; ++j)
        acc[i][j] = __builtin_amdgcn_mfma_f32_16x16x32_bf16(af[i], wf[j], acc[i][j], 0, 0, 0);
    for (int i = 0; i < 4; ++i) af[i] = *(const short8*)&As[(wr + i*16 + l16)*64 + qsr1];
    for (int j = 0; j < 4; ++j) wf[j] = *(const short8*)&Ws[(wc + j*16 + l16)*64 + qsr1];
    for (int i = 0; i < 4; ++i)
      for (int j = 0; j < 4; ++j)
        acc[i][j] = __builtin_amdgcn_mfma_f32_16x16x32_bf16(af[i], wf[j], acc[i][j], 0, 0, 0);
  }
  for (int i = 0; i < 4; ++i) {
    int r0 = row0 + wr + i*16 + quad*4;
    for (int j = 0; j < 4; ++j) {
      int cc = col0 + wc + j*16 + l16;
      for (int r = 0; r < 4; ++r) {
        float v = acc[i][j][r];
        size_t idx = (size_t)(r0 + r) * N + cc;
        if (MODE == 0) {
          ((short*)Cv)[idx] = f2bf(v);
        } else {
          ((float*)Cv)[idx] = v + X[idx];
        }
      }
    }
  }
}

// ------------- GELU branch: branch[:,0:1024] = lin * gelu(pre), bf16 -------------
__global__ __launch_bounds__(256) void gelu_kernel(const short* __restrict__ proj,
    short* __restrict__ branch) {
  int row = blockIdx.x;
  int c = threadIdx.x * 4;
  const short* pr = proj + (size_t)row * PROJC;
  short4v lin = *(const short4v*)(pr + 3*DIMD + c);
  short4v pre = *(const short4v*)(pr + 4*DIMD + c);
  short4v o;
  for (int i = 0; i < 4; ++i) {
    float xx = bf2f(pre[i]);
    float g = 0.5f * xx * (1.f + erff(xx * 0.70710678118654752f));
    o[i] = f2bf(bf2f(lin[i]) * g);
  }
  *(short4v*)(branch + (size_t)row * BRC + c) = o;
}

// ------------- V transpose: vt[bh][d][l] from proj v-slice (bf16) -------------
__global__ __launch_bounds__(256) void vt_kernel(const short* __restrict__ proj,
    short* __restrict__ vt) {
  int bh = blockIdx.y;
  int b = bh >> 3, hh = bh & 7;
  int l0 = blockIdx.x * 64;
  __shared__ short Ls[64][136];
  int tid = threadIdx.x;
  int r = tid >> 4, c = (tid & 15) * 8;
  const short* Vp = proj + (size_t)b * LSEQ * PROJC + 2*DIMD + hh*HD;
  for (int p = 0; p < 4; ++p)
    *(short8*)&Ls[r + p*16][c] = *(const short8*)(Vp + (size_t)(l0 + r + p*16) * PROJC + c);
  __syncthreads();
  int d = tid >> 1, lh = (tid & 1) * 32;
  short* outp = vt + ((size_t)bh * HD + d) * LSEQ + l0 + lh;
  for (int g = 0; g < 4; ++g) {
    short8 o;
    for (int j = 0; j < 8; ++j) o[j] = Ls[lh + g*8 + j][d];
    *(short8*)(outp + g*8) = o;
  }
}

// ------------- Flash attention, p=2 power-softmax, causal, load-balanced.
// Round-6 verified structure: pairing qa=bid (waves 0-3), qb=31-bid (waves
// 4-7), uniform 33 tile-steps/block. K staged 64 wide, computed as two
// 32-col halves. No running max (scores ~N(0,1): exp(2s)<=~e^12 << fp32
// range); l accumulated per-lane, reduced once at the end. -------------
__global__ __launch_bounds__(512) void attn_kernel(const short* __restrict__ proj,
    const short* __restrict__ vt, short* __restrict__ branch) {
  int bh = blockIdx.y;
  int b = bh >> 3, hh = bh & 7;
  int bid = blockIdx.x;            // 0..15
  int tid = threadIdx.x;           // 0..511
  int wv = tid >> 6, lane = tid & 63, quad = lane >> 4, l16 = lane & 15;
  int qsel = (wv < 4) ? bid : (31 - bid);
  int qw = qsel * 64 + (wv & 3) * 16;

  const short* Qp  = proj + (size_t)b * LSEQ * PROJC + hh*HD;
  const short* Kp  = Qp + DIMD;
  const short* VTp = vt + (size_t)bh * HD * LSEQ;

  __shared__ short Ks[64][136];
  __shared__ short Vs[128][76];
  __shared__ short Ps[8][16][44];

  short8 qf[4];
  {
    const short* qrow = Qp + (size_t)(qw + l16) * PROJC;
    for (int s = 0; s < 4; ++s) qf[s] = *(const short8*)(qrow + s*32 + quad*8);
  }
  float lsum[4] = {0.f, 0.f, 0.f, 0.f};
  floatx4 O[8] = {};

  const float scale = 0.08838834764831845f;  // 1/sqrt(128)
  int NT = 32 - bid;               // staged 64-wide tiles (qb's causal range)
  int krow = tid >> 4;             // 0..31
  int kcol = (tid & 15) * 8;
  int vd = tid >> 2;               // 0..127
  int vk = (tid & 3) * 8;
  for (int kt = 0; kt < NT; ++kt) {
    int kb64 = kt * 64;
    short8 kv0 = *(const short8*)(Kp + (size_t)(kb64 + krow) * PROJC + kcol);
    short8 kv1 = *(const short8*)(Kp + (size_t)(kb64 + 32 + krow) * PROJC + kcol);
    short8 vv0 = *(const short8*)(VTp + (size_t)vd * LSEQ + kb64 + vk);
    short8 vv1 = *(const short8*)(VTp + (size_t)vd * LSEQ + kb64 + 32 + vk);
    __syncthreads();
    *(short8*)&Ks[krow][kcol]      = kv0;
    *(short8*)&Ks[krow + 32][kcol] = kv1;
    *(short8*)&Vs[vd][vk]          = vv0;
    *(short8*)&Vs[vd][32 + vk]     = vv1;
    __syncthreads();
    for (int hf = 0; hf < 2; ++hf) {
      int kb = kb64 + hf*32;
      if (kb <= qw + 15) {
        floatx4 s0 = {0.f,0.f,0.f,0.f}, s1 = {0.f,0.f,0.f,0.f};
        for (int s = 0; s < 4; ++s) {
          short8 kf0 = *(const short8*)&Ks[hf*32 + l16][s*32 + quad*8];
          short8 kf1 = *(const short8*)&Ks[hf*32 + 16 + l16][s*32 + quad*8];
          s0 = __builtin_amdgcn_mfma_f32_16x16x32_bf16(qf[s], kf0, s0, 0, 0, 0);
          s1 = __builtin_amdgcn_mfma_f32_16x16x32_bf16(qf[s], kf1, s1, 0, 0, 0);
        }
        int c0 = kb + l16, c1 = kb + 16 + l16;
        for (int r = 0; r < 4; ++r) {
          int q = qw + quad*4 + r;
          float w0 = (c0 <= q) ? __expf(s0[r] * scale) : 0.f;
          float w1 = (c1 <= q) ? __expf(s1[r] * scale) : 0.f;
          lsum[r] += w0*w0 + w1*w1;
          Ps[wv][quad*4+r][l16]      = f2bf(w0);
          Ps[wv][quad*4+r][16 + l16] = f2bf(w1);
        }
        asm volatile("s_waitcnt lgkmcnt(0)" ::: "memory");
        short8 pf = *(const short8*)&Ps[wv][l16][quad*8];
        for (int t8 = 0; t8 < 8; ++t8) {
          short8 vf = *(const short8*)&Vs[t8*16 + l16][hf*32 + quad*8];
          O[t8] = __builtin_amdgcn_mfma_f32_16x16x32_bf16(pf, vf, O[t8], 0, 0, 0);
        }
      }
    }
  }
  for (int r = 0; r < 4; ++r) {
    float l = lsum[r];
    for (int off = 1; off < 16; off <<= 1) l += __shfl_xor(l, off);
    float inv = rsqrtf(l);
    int q = qw + quad*4 + r;
    short* orow = branch + ((size_t)(b*LSEQ + q)) * BRC + DIMD + hh*HD;
    for (int t8 = 0; t8 < 8; ++t8)
      orow[t8*16 + l16] = f2bf(O[t8][r] * inv);
  }
}

extern "C" void kernel_launch(void* const* d_in, const int* in_sizes, int n_in,
                              void* d_out, int out_size, void* d_ws, size_t ws_size,
                              hipStream_t stream) {
  const float* x     = (const float*)d_in[0];
  const float* gamma = (const float*)d_in[1];
  const float* beta  = (const float*)d_in[2];
  const float* w_qkv = (const float*)d_in[3];
  const float* w_out = (const float*)d_in[4];
  float* out = (float*)d_out;

  char* ws = (char*)d_ws;
  short* h      = (short*)ws;                                 // 16 MB (reused as vt)
  short* proj   = (short*)(ws + (size_t)16*1024*1024);        // 80 MB
  short* branch = (short*)(ws + (size_t)96*1024*1024);        // 32 MB
  short* wq     = (short*)(ws + (size_t)128*1024*1024);       // 10 MB
  short* wo     = (short*)(ws + (size_t)138*1024*1024);       // 4 MB
  short* vt     = h;  // h dead after GEMM1; alias for V^T

  int n1 = PROJC*DIMD/4, n2 = DIMD*BRC/4;
  cvt2_kernel<<<(n1 + n2 + 255)/256, 256, 0, stream>>>(w_qkv, wq, n1, w_out, wo, n2);
  ln_kernel<<<NROWS, 256, 0, stream>>>(x, gamma, beta, h);
  gemm_bt<0><<<dim3(PROJC/128, NROWS/128), 256, 0, stream>>>(h, wq, nullptr, proj,
                                                             NROWS, PROJC, DIMD);
  gelu_kernel<<<NROWS, 256, 0, stream>>>(proj, branch);
  vt_kernel<<<dim3(LSEQ/64, BATCH*NHEAD), 256, 0, stream>>>(proj, vt);
  attn_kernel<<<dim3(16, BATCH*NHEAD), 512, 0, stream>>>(proj, vt, branch);
  gemm_bt<1><<<dim3(DIMD/128, NROWS/128), 256, 0, stream>>>(branch, wo, x, out,
                                                            NROWS, DIMD, BRC);
}